// Round 1
// baseline (1312.329 us; speedup 1.0000x reference)
//
#include <hip/hip_runtime.h>

// ---------------- CSR build ----------------

__global__ void degree_kernel(const int* __restrict__ ei, int* __restrict__ deg, int E) {
    int e = blockIdx.x * blockDim.x + threadIdx.x;
    if (e < E) {
        int dst = ei[E + e];
        atomicAdd(&deg[dst], 1);
    }
}

__global__ void scan_inv_kernel(const int* __restrict__ deg, int* __restrict__ offs,
                                float* __restrict__ invd, int n) {
    __shared__ int sums[1024];
    int tid = threadIdx.x;
    int chunk = (n + 1023) >> 10;
    int start = tid * chunk;
    int end = min(start + chunk, n);
    int s = 0;
    for (int i = start; i < end; i++) s += deg[i];
    sums[tid] = s;
    __syncthreads();
    for (int off = 1; off < 1024; off <<= 1) {
        int v = 0;
        if (tid >= off) v = sums[tid - off];
        __syncthreads();
        if (tid >= off) sums[tid] += v;
        __syncthreads();
    }
    int base = (tid == 0) ? 0 : sums[tid - 1];
    for (int i = start; i < end; i++) {
        offs[i] = base;
        int d = deg[i];
        base += d;
        invd[i] = 1.0f / (float)(d > 0 ? d : 1);
    }
    if (tid == 0) offs[n] = sums[1023];
}

__global__ void fill_kernel(const int* __restrict__ ei, const int* __restrict__ offs,
                            int* __restrict__ cursor, int* __restrict__ csr, int E) {
    int e = blockIdx.x * blockDim.x + threadIdx.x;
    if (e < E) {
        int src = ei[e];
        int dst = ei[E + e];
        int pos = atomicAdd(&cursor[dst], 1);
        csr[offs[dst] + pos] = src;
    }
}

// ---------------- mean aggregation: one wave per node ----------------

template <int D>
__global__ __launch_bounds__(256) void aggregate_kernel(
    const float* __restrict__ h, const int* __restrict__ offs,
    const int* __restrict__ csr, const float* __restrict__ invd,
    float* __restrict__ mean, int nN)
{
    int wid = blockIdx.x * 4 + (threadIdx.x >> 6);
    int lane = threadIdx.x & 63;
    if (wid >= nN) return;
    int o0 = offs[wid], o1 = offs[wid + 1];
    constexpr int C = D / 64;
    float acc[C];
#pragma unroll
    for (int c = 0; c < C; c++) acc[c] = 0.f;
    int j = o0;
    for (; j + 1 < o1; j += 2) {
        int s0 = csr[j], s1 = csr[j + 1];
        const float* r0 = h + (size_t)s0 * D;
        const float* r1 = h + (size_t)s1 * D;
#pragma unroll
        for (int c = 0; c < C; c++) acc[c] += r0[lane + 64 * c];
#pragma unroll
        for (int c = 0; c < C; c++) acc[c] += r1[lane + 64 * c];
    }
    if (j < o1) {
        const float* r0 = h + (size_t)csr[j] * D;
#pragma unroll
        for (int c = 0; c < C; c++) acc[c] += r0[lane + 64 * c];
    }
    float iv = invd[wid];
#pragma unroll
    for (int c = 0; c < C; c++) mean[(size_t)wid * D + lane + 64 * c] = acc[c] * iv;
}

// ---------------- fused dual GEMM + bias + ReLU ----------------
// out[n,m] = relu( sum_k A1[n,k]*wl[k,m] + bias[m] + sum_k A2[n,k]*wr[k,m] )
// 64-row tile per block, A staged transposed in LDS, W streamed via L1/L2.

template <int K, int M>
__global__ __launch_bounds__(256) void gemm_relu_kernel(
    const float* __restrict__ A1, const float* __restrict__ A2,
    const float* __restrict__ wl, const float* __restrict__ wr,
    const float* __restrict__ bias, float* __restrict__ out, int nN)
{
    constexpr int TX = M / 4;       // threads across columns (float4 each)
    constexpr int TY = 256 / TX;
    constexpr int TR = 64 / TY;     // rows per thread
    __shared__ float a_s[32][65];   // [k-chunk][row], padded

    int tid = threadIdx.x;
    int tx = tid % TX, ty = tid / TX;
    int n0 = blockIdx.x * 64;

    float4 bv = *(const float4*)(bias + tx * 4);
    float4 acc[TR];
#pragma unroll
    for (int r = 0; r < TR; r++) acc[r] = bv;

    int lr = tid >> 3;            // 0..31
    int lc = (tid & 7) << 2;      // 0,4,...,28

#pragma unroll
    for (int pass = 0; pass < 2; pass++) {
        const float* __restrict__ A = pass ? A2 : A1;
        const float* __restrict__ W = pass ? wr : wl;
        for (int k0 = 0; k0 < K; k0 += 32) {
            __syncthreads();   // protect previous chunk's reads
#pragma unroll
            for (int rr = 0; rr < 64; rr += 32) {
                int gr = n0 + lr + rr;
                float4 v = make_float4(0.f, 0.f, 0.f, 0.f);
                if (gr < nN) v = *(const float4*)(A + (size_t)gr * K + k0 + lc);
                a_s[lc + 0][lr + rr] = v.x;
                a_s[lc + 1][lr + rr] = v.y;
                a_s[lc + 2][lr + rr] = v.z;
                a_s[lc + 3][lr + rr] = v.w;
            }
            __syncthreads();
#pragma unroll
            for (int kk = 0; kk < 32; kk++) {
                float4 w4 = *(const float4*)(W + (size_t)(k0 + kk) * M + tx * 4);
#pragma unroll
                for (int r = 0; r < TR; r++) {
                    float a = a_s[kk][ty * TR + r];
                    acc[r].x = fmaf(a, w4.x, acc[r].x);
                    acc[r].y = fmaf(a, w4.y, acc[r].y);
                    acc[r].z = fmaf(a, w4.z, acc[r].z);
                    acc[r].w = fmaf(a, w4.w, acc[r].w);
                }
            }
        }
    }

#pragma unroll
    for (int r = 0; r < TR; r++) {
        int n = n0 + ty * TR + r;
        if (n < nN) {
            float4 v = acc[r];
            v.x = fmaxf(v.x, 0.f); v.y = fmaxf(v.y, 0.f);
            v.z = fmaxf(v.z, 0.f); v.w = fmaxf(v.w, 0.f);
            *(float4*)(out + (size_t)n * M + tx * 4) = v;
        }
    }
}

// ---------------- classifier: [N,32] @ [32,2] + bc ----------------

__global__ void classifier_kernel(const float* __restrict__ h,
                                  const float* __restrict__ wc,
                                  const float* __restrict__ bc,
                                  float* __restrict__ out, int nN) {
    int n = blockIdx.x * blockDim.x + threadIdx.x;
    if (n >= nN) return;
    float a0 = bc[0], a1 = bc[1];
    const float* row = h + (size_t)n * 32;
#pragma unroll
    for (int k = 0; k < 32; k++) {
        float v = row[k];
        a0 = fmaf(v, wc[k * 2 + 0], a0);
        a1 = fmaf(v, wc[k * 2 + 1], a1);
    }
    out[n * 2 + 0] = a0;
    out[n * 2 + 1] = a1;
}

// ---------------- launch ----------------

extern "C" void kernel_launch(void* const* d_in, const int* in_sizes, int n_in,
                              void* d_out, int out_size, void* d_ws, size_t ws_size,
                              hipStream_t stream) {
    const float* x   = (const float*)d_in[0];
    const int*   ei  = (const int*)d_in[1];   // [2,E] int32 (JAX x64 off)
    const float* w1l = (const float*)d_in[2];
    const float* b1l = (const float*)d_in[3];
    const float* w1r = (const float*)d_in[4];
    const float* w2l = (const float*)d_in[5];
    const float* b2l = (const float*)d_in[6];
    const float* w2r = (const float*)d_in[7];
    const float* w3l = (const float*)d_in[8];
    const float* b3l = (const float*)d_in[9];
    const float* w3r = (const float*)d_in[10];
    const float* wc  = (const float*)d_in[11];
    const float* bc  = (const float*)d_in[12];
    float* out = (float*)d_out;

    const int N = in_sizes[0] / 128;
    const int E = in_sizes[1] / 2;

    char* p = (char*)d_ws;
    auto alloc = [&](size_t bytes) {
        char* r = p;
        p += (bytes + 511) & ~(size_t)511;
        return r;
    };
    int*   deg    = (int*)  alloc((size_t)N * 4);
    int*   offs   = (int*)  alloc(((size_t)N + 1) * 4);
    int*   cursor = (int*)  alloc((size_t)N * 4);
    float* invd   = (float*)alloc((size_t)N * 4);
    int*   csr    = (int*)  alloc((size_t)E * 4);
    float* mean   = (float*)alloc((size_t)N * 128 * 4);
    float* h1     = (float*)alloc((size_t)N * 128 * 4);
    float* h2     = (float*)alloc((size_t)N * 64 * 4);
    float* h3     = (float*)alloc((size_t)N * 32 * 4);

    hipMemsetAsync(deg, 0, (size_t)N * 4, stream);
    hipMemsetAsync(cursor, 0, (size_t)N * 4, stream);

    int eb = (E + 255) / 256;
    degree_kernel<<<eb, 256, 0, stream>>>(ei, deg, E);
    scan_inv_kernel<<<1, 1024, 0, stream>>>(deg, offs, invd, N);
    fill_kernel<<<eb, 256, 0, stream>>>(ei, offs, cursor, csr, E);

    int ab = (N + 3) / 4;
    int gb = (N + 63) / 64;

    aggregate_kernel<128><<<ab, 256, 0, stream>>>(x, offs, csr, invd, mean, N);
    gemm_relu_kernel<128, 128><<<gb, 256, 0, stream>>>(mean, x, w1l, w1r, b1l, h1, N);

    aggregate_kernel<128><<<ab, 256, 0, stream>>>(h1, offs, csr, invd, mean, N);
    gemm_relu_kernel<128, 64><<<gb, 256, 0, stream>>>(mean, h1, w2l, w2r, b2l, h2, N);

    aggregate_kernel<64><<<ab, 256, 0, stream>>>(h2, offs, csr, invd, mean, N);
    gemm_relu_kernel<64, 32><<<gb, 256, 0, stream>>>(mean, h2, w3l, w3r, b3l, h3, N);

    classifier_kernel<<<(N + 255) / 256, 256, 0, stream>>>(h3, wc, bc, out, N);
}